// Round 11
// baseline (130.649 us; speedup 1.0000x reference)
//
#include <hip/hip_runtime.h>
#include <hip/hip_fp16.h>

#define D_FEAT 64
#define NPB 128            // nodes per dst bucket (node >> 7)
#define NBMAX 1024         // dst bucket count (pow2)
#define SBSH 9             // src bucket shift
#define SNPB 512           // nodes per src bucket
#define SBMAX 256          // src bucket slots (pow2)
#define CHUNK 4096         // edges per partition block (arrA run = 4 ints)
#define EPT 16             // CHUNK / 256
#define CAPB 2816          // full-bucket capacity bound for fit path
#define CAPB_H 1536        // half-bucket srcS capacity (mean 1023 + ~16 sigma)

// ---------------- zero ----------------
__global__ void zero_ints(int* __restrict__ p, int n) {
    int i = blockIdx.x * blockDim.x + threadIdx.x;
    int stride = gridDim.x * blockDim.x;
    for (int j = i; j < n; j += stride) p[j] = 0;
}

// ---------------- bucket counts: dst (1024 bins) + src (256 bins) ----------------
__global__ __launch_bounds__(256) void bcnt_kernel(
        const int* __restrict__ src, const int* __restrict__ dst, int n_edges,
        int* __restrict__ dbcnt8, int* __restrict__ sbcnt8) {
    __shared__ int ld[NBMAX];
    __shared__ int ls[SBMAX];
    int t = threadIdx.x;
    for (int i = t; i < NBMAX; i += 256) ld[i] = 0;
    if (t < SBMAX) ls[t] = 0;
    __syncthreads();
    int i0 = blockIdx.x * blockDim.x + t;
    int stride = gridDim.x * blockDim.x;
    for (int e = i0; e < n_edges; e += stride) {
        atomicAdd(&ld[dst[e] >> 7], 1);
        atomicAdd(&ls[src[e] >> SBSH], 1);
    }
    __syncthreads();
    int* dmy = dbcnt8 + (blockIdx.x & 7) * NBMAX;
    int* smy = sbcnt8 + (blockIdx.x & 7) * SBMAX;
    for (int i = t; i < NBMAX; i += 256) {
        if (ld[i]) atomicAdd(&dmy[i], ld[i]);
    }
    if (t < SBMAX && ls[t]) atomicAdd(&smy[t], ls[t]);
}

// ---------------- dual exclusive scan: block 0 = dst (1024), block 1 = src (256) --
__global__ void scan2_kernel(const int* __restrict__ dbcnt8, const int* __restrict__ sbcnt8,
                             int* __restrict__ dbstart, int* __restrict__ gcursor,
                             int* __restrict__ sbstart, int* __restrict__ scursor,
                             int n_edges) {
    __shared__ int wsum[16];
    int t = threadIdx.x, lane = t & 63, w = t >> 6;
    if (blockIdx.x == 0) {
        int v = 0;
        #pragma unroll
        for (int c = 0; c < 8; ++c) v += dbcnt8[c * NBMAX + t];
        int inc = v;
        #pragma unroll
        for (int off = 1; off < 64; off <<= 1) {
            int y = __shfl_up(inc, off);
            if (lane >= off) inc += y;
        }
        if (lane == 63) wsum[w] = inc;
        __syncthreads();
        int add = 0;
        #pragma unroll
        for (int i = 0; i < 15; ++i) if (i < w) add += wsum[i];
        int ex = add + inc - v;
        dbstart[t] = ex;
        gcursor[t] = ex;
        if (t == NBMAX - 1) dbstart[NBMAX] = n_edges;
    } else {
        int v = 0, inc = 0;
        if (t < SBMAX) {
            #pragma unroll
            for (int c = 0; c < 8; ++c) v += sbcnt8[c * SBMAX + t];
            inc = v;
            #pragma unroll
            for (int off = 1; off < 64; off <<= 1) {
                int y = __shfl_up(inc, off);
                if (lane >= off) inc += y;
            }
            if (lane == 63) wsum[w] = inc;
        }
        __syncthreads();
        if (t < SBMAX) {
            int add = 0;
            #pragma unroll
            for (int i = 0; i < 3; ++i) if (i < w) add += wsum[i];
            int ex = add + inc - v;
            sbstart[t] = ex;
            scursor[t] = ex;
            if (t == SBMAX - 1) sbstart[SBMAX] = n_edges;
        }
    }
}

// ---------------- fused dual partition ----------------
// Phase D: arrA[pk = (src<<7)|(dst&127)] bucketed by dst>>7
// Phase S: arrS16[src&511 ushort] bucketed by src>>9
__global__ __launch_bounds__(256) void dualpart_kernel(
        const int* __restrict__ src, const int* __restrict__ dst, int n_edges,
        int* __restrict__ gcursor, int* __restrict__ scursor,
        int* __restrict__ arrA, unsigned short* __restrict__ arrS16) {
    __shared__ int lhist[NBMAX];
    __shared__ int lstart[NBMAX];
    __shared__ int ldelta[NBMAX];
    __shared__ int lcur[NBMAX];
    __shared__ int part[256];
    __shared__ int pkLDS[CHUNK];
    __shared__ unsigned short bktLDS[CHUNK];

    int t = threadIdx.x;
    long long cbase = (long long)blockIdx.x * CHUNK;
    int cnt = (n_edges - cbase < CHUNK) ? (int)(n_edges - cbase) : CHUNK;

    for (int i = t; i < NBMAX; i += 256) lhist[i] = 0;
    __syncthreads();

    int ssrc[EPT], sdst[EPT];
    #pragma unroll
    for (int i = 0; i < EPT; ++i) {
        long long e = cbase + t + i * 256;
        if (e < n_edges) {
            ssrc[i] = src[e];
            sdst[i] = dst[e];
            atomicAdd(&lhist[sdst[i] >> 7], 1);
        } else {
            ssrc[i] = -1;
            sdst[i] = -1;
        }
    }
    __syncthreads();

    // ---- phase D scan ----
    int b0 = 4 * t;
    int h0 = lhist[b0], h1 = lhist[b0 + 1], h2v = lhist[b0 + 2], h3 = lhist[b0 + 3];
    int tot = h0 + h1 + h2v + h3;
    part[t] = tot;
    __syncthreads();
    for (int off = 1; off < 256; off <<= 1) {
        int x = (t >= off) ? part[t - off] : 0;
        __syncthreads();
        part[t] += x;
        __syncthreads();
    }
    int ex = part[t] - tot;
    lstart[b0] = ex;
    lstart[b0 + 1] = ex + h0;
    lstart[b0 + 2] = ex + h0 + h1;
    lstart[b0 + 3] = ex + h0 + h1 + h2v;
    __syncthreads();
    for (int b = t; b < NBMAX; b += 256) {
        lcur[b] = lstart[b];
        int c = lhist[b];
        if (c > 0) ldelta[b] = atomicAdd(&gcursor[b], c) - lstart[b];
    }
    __syncthreads();
    #pragma unroll
    for (int i = 0; i < EPT; ++i) {
        if (sdst[i] >= 0) {
            int b = sdst[i] >> 7;
            int slot = atomicAdd(&lcur[b], 1);
            pkLDS[slot] = (ssrc[i] << 7) | (sdst[i] & 127);
            bktLDS[slot] = (unsigned short)b;
        }
    }
    __syncthreads();
    for (int j = t; j < cnt; j += 256) {
        int b = bktLDS[j];
        arrA[j + ldelta[b]] = pkLDS[j];
    }
    __syncthreads();

    // ---- phase S (coarse 256-bin, ushort payload) ----
    if (t < SBMAX) lhist[t] = 0;
    __syncthreads();
    #pragma unroll
    for (int i = 0; i < EPT; ++i) {
        if (ssrc[i] >= 0) atomicAdd(&lhist[ssrc[i] >> SBSH], 1);
    }
    __syncthreads();
    int h = lhist[t];
    part[t] = h;
    __syncthreads();
    for (int off = 1; off < 256; off <<= 1) {
        int x = (t >= off) ? part[t - off] : 0;
        __syncthreads();
        part[t] += x;
        __syncthreads();
    }
    ex = part[t] - h;
    lcur[t] = ex;
    if (h > 0) ldelta[t] = atomicAdd(&scursor[t], h) - ex;
    __syncthreads();
    unsigned short* stg = (unsigned short*)pkLDS;
    #pragma unroll
    for (int i = 0; i < EPT; ++i) {
        if (ssrc[i] >= 0) {
            int b = ssrc[i] >> SBSH;
            int slot = atomicAdd(&lcur[b], 1);
            stg[slot] = (unsigned short)(ssrc[i] & (SNPB - 1));
            bktLDS[slot] = (unsigned short)b;
        }
    }
    __syncthreads();
    for (int j = t; j < cnt; j += 256) {
        int b = bktLDS[j];
        arrS16[j + ldelta[b]] = stg[j];
    }
}

// ---------------- out-degree -> oscale (one block per src bucket) ----------------
__global__ __launch_bounds__(256) void scount_kernel(
        const unsigned short* __restrict__ arrS16, const int* __restrict__ sbstart,
        float* __restrict__ oscale, int n_nodes) {
    __shared__ int lh[SNPB];
    int b = blockIdx.x, t = threadIdx.x;
    int s = sbstart[b], e = sbstart[b + 1];
    for (int i = t; i < SNPB; i += 256) lh[i] = 0;
    __syncthreads();
    for (int i = s + t; i < e; i += 256) atomicAdd(&lh[arrS16[i]], 1);
    __syncthreads();
    int nbase = b * SNPB;
    for (int i = t; i < SNPB; i += 256) {
        int node = nbase + i;
        if (node < n_nodes) {
            int od = lh[i];
            oscale[node] = rsqrtf((float)(od > 1 ? od : 1));
        }
    }
}

// ---------------- h prepass (grid-stride, full device) ----------------
__global__ void h_prepass_kernel(const float4* __restrict__ emb4,
                                 const float* __restrict__ oscale,
                                 uint2* __restrict__ h2, int n_total, int n_nodes) {
    int i = blockIdx.x * blockDim.x + threadIdx.x;
    int stride = gridDim.x * blockDim.x;
    for (int j = i; j < n_total; j += stride) {
        int node = j >> 4;
        uint2 r;
        if (node < n_nodes) {
            float s = oscale[node];
            float4 v = emb4[j];
            __half2 a = __floats2half2_rn(v.x * s, v.y * s);
            __half2 b = __floats2half2_rn(v.z * s, v.w * s);
            union { __half2 h; unsigned int u; } ua, ub;
            ua.h = a; ub.h = b;
            r.x = ua.u; r.y = ub.u;
        } else {
            r.x = 0; r.y = 0;
        }
        h2[j] = r;
    }
}

// ---------------- fused sort + aggregate: 2 blocks/bucket, 256 thr, 2-pass read ----
__global__ __launch_bounds__(256) void sortagg_kernel(
        const uint2* __restrict__ h2, const int* __restrict__ arrA,
        const int* __restrict__ dbstart, float* __restrict__ out, int n_nodes) {
    __shared__ int lh[64];
    __shared__ int lst[64];
    __shared__ int lcur[64];
    __shared__ int srcS[CAPB_H];
    int b = blockIdx.x >> 1, half = blockIdx.x & 1;
    int t = threadIdx.x;
    int s = dbstart[b], e = dbstart[b + 1];
    int cnt = e - s;

    if (t < 64) lh[t] = 0;
    __syncthreads();
    // pass 1: histogram of this half's nodes
    for (int i = t; i < cnt; i += 256) {
        int v = arrA[s + i];
        if (((v >> 6) & 1) == half) atomicAdd(&lh[v & 63], 1);
    }
    __syncthreads();
    if (t < 64) {
        int l0 = lh[t];
        int a = l0;
        #pragma unroll
        for (int off = 1; off < 64; off <<= 1) {
            int y = __shfl_up(a, off);
            if (t >= off) a += y;
        }
        lst[t] = a - l0;
        lcur[t] = a - l0;
    }
    __syncthreads();
    int halfcnt = lst[63] + lh[63];
    bool useS = (halfcnt <= CAPB_H);
    if (useS) {
        // pass 2 (L2-hot): scatter into sorted LDS
        for (int i = t; i < cnt; i += 256) {
            int v = arrA[s + i];
            if (((v >> 6) & 1) == half) {
                int slot = atomicAdd(&lcur[v & 63], 1);
                srcS[slot] = v >> 7;
            }
        }
    }
    __syncthreads();

    int w = t >> 6, L = t & 63, g = L >> 4, c = L & 15;
    int nbase = b * NPB + half * 64;
    union { unsigned int u; __half2 h; } uc;
    for (int nl = w * 16; nl < w * 16 + 16; ++nl) {
        int node = nbase + nl;
        if (node >= n_nodes) break;
        int st = lst[nl];
        int deg = lh[nl];
        int en = st + deg;
        float ax = 0.f, ay = 0.f, az = 0.f, aw = 0.f;
        if (useS) {
            for (int eidx = st; eidx < en; eidx += 16) {
                int ea = eidx + g, eb = ea + 4, ec = ea + 8, ed = ea + 12;
                int sa = (ea < en) ? srcS[ea] : n_nodes;
                int sb = (eb < en) ? srcS[eb] : n_nodes;
                int sc = (ec < en) ? srcS[ec] : n_nodes;
                int sd = (ed < en) ? srcS[ed] : n_nodes;
                uint2 va = h2[(size_t)sa * 16 + c];
                uint2 vb = h2[(size_t)sb * 16 + c];
                uint2 vc = h2[(size_t)sc * 16 + c];
                uint2 vd = h2[(size_t)sd * 16 + c];
                float2 f;
                uc.u = va.x; f = __half22float2(uc.h); ax += f.x; ay += f.y;
                uc.u = va.y; f = __half22float2(uc.h); az += f.x; aw += f.y;
                uc.u = vb.x; f = __half22float2(uc.h); ax += f.x; ay += f.y;
                uc.u = vb.y; f = __half22float2(uc.h); az += f.x; aw += f.y;
                uc.u = vc.x; f = __half22float2(uc.h); ax += f.x; ay += f.y;
                uc.u = vc.y; f = __half22float2(uc.h); az += f.x; aw += f.y;
                uc.u = vd.x; f = __half22float2(uc.h); ax += f.x; ay += f.y;
                uc.u = vd.y; f = __half22float2(uc.h); az += f.x; aw += f.y;
            }
        } else {
            int hv = (half << 6) | nl;
            for (int i2 = g; i2 < cnt; i2 += 4) {
                int v = arrA[s + i2];
                if ((v & 127) == hv) {
                    int sa = v >> 7;
                    uint2 va = h2[(size_t)sa * 16 + c];
                    float2 f;
                    uc.u = va.x; f = __half22float2(uc.h); ax += f.x; ay += f.y;
                    uc.u = va.y; f = __half22float2(uc.h); az += f.x; aw += f.y;
                }
            }
        }
        ax += __shfl_xor(ax, 16); ay += __shfl_xor(ay, 16);
        az += __shfl_xor(az, 16); aw += __shfl_xor(aw, 16);
        ax += __shfl_xor(ax, 32); ay += __shfl_xor(ay, 32);
        az += __shfl_xor(az, 32); aw += __shfl_xor(aw, 32);
        if (g == 0) {
            float is = rsqrtf((float)(deg > 1 ? deg : 1));
            float4 r;
            r.x = ax * is; r.y = ay * is; r.z = az * is; r.w = aw * is;
            ((float4*)out)[(size_t)node * 16 + c] = r;
        }
    }
}

// ---------------- fallback: atomic scatter path (tiny ws) ----------------
__global__ void fb_zero(float* __restrict__ out, long long n_out,
                        int* __restrict__ deg, int n_deg) {
    long long i = (long long)blockIdx.x * blockDim.x + threadIdx.x;
    long long stride = (long long)gridDim.x * blockDim.x;
    for (long long j = i; j < n_out; j += stride) out[j] = 0.0f;
    for (long long j = i; j < n_deg; j += stride) deg[j] = 0;
}

__global__ void fb_degree(const int* __restrict__ src, const int* __restrict__ dst,
                          int n_edges, int* __restrict__ outdeg, int* __restrict__ indeg) {
    int i = blockIdx.x * blockDim.x + threadIdx.x;
    int stride = gridDim.x * blockDim.x;
    for (int e = i; e < n_edges; e += stride) {
        atomicAdd(&outdeg[src[e]], 1);
        atomicAdd(&indeg[dst[e]], 1);
    }
}

__global__ void fb_scatter(const float* __restrict__ emb,
                           const int* __restrict__ src, const int* __restrict__ dst,
                           const int* __restrict__ outdeg,
                           float* __restrict__ out, int n_edges) {
    const int epb = blockDim.x >> 6;
    const int d = threadIdx.x & 63;
    long long e0 = (long long)blockIdx.x * epb + (threadIdx.x >> 6);
    long long estride = (long long)gridDim.x * epb;
    for (long long e = e0; e < n_edges; e += estride) {
        int s = src[e];
        int tt = dst[e];
        int od = outdeg[s];
        float v = emb[(long long)s * D_FEAT + d] * rsqrtf((float)(od > 1 ? od : 1));
        atomicAdd(&out[(long long)tt * D_FEAT + d], v);
    }
}

__global__ void fb_scale(float* __restrict__ out, const int* __restrict__ indeg,
                         long long n_elems) {
    long long i = (long long)blockIdx.x * blockDim.x + threadIdx.x;
    long long stride = (long long)gridDim.x * blockDim.x;
    for (long long j = i; j < n_elems; j += stride) {
        int id = indeg[(int)(j >> 6)];
        out[j] *= rsqrtf((float)(id > 1 ? id : 1));
    }
}

extern "C" void kernel_launch(void* const* d_in, const int* in_sizes, int n_in,
                              void* d_out, int out_size, void* d_ws, size_t ws_size,
                              hipStream_t stream) {
    const float* emb = (const float*)d_in[0];
    const int* src = (const int*)d_in[1];
    const int* dst = (const int*)d_in[2];
    const int n_nodes = in_sizes[0] / D_FEAT;
    const int n_edges = in_sizes[1];
    float* out = (float*)d_out;
    const int block = 256;
    const int nb = (n_nodes + NPB - 1) / NPB;
    const int nb2 = (n_nodes + SNPB - 1) / SNPB;
    const int K = NBMAX;

    // layout (ints): oscale | dbcnt8 | sbcnt8 | dbstart | gcursor | sbstart |
    //                scursor | arrA | region{arrS16 -> h2}
    float* oscale = (float*)d_ws;                    // N
    int* dbcnt8 = (int*)(oscale + n_nodes);          // 8K
    int* sbcnt8 = dbcnt8 + 8 * K;                    // 8*SBMAX
    int* dbstart = sbcnt8 + 8 * SBMAX;               // K+1
    int* gcursor = dbstart + K + 1;                  // K
    int* sbstart = gcursor + K;                      // SBMAX+1
    int* scursor = sbstart + SBMAX + 1;              // SBMAX
    int* arrA = scursor + SBMAX;                     // E
    int* region = arrA + n_edges;                    // max(E/2, (N+1)*32) ints
    unsigned short* arrS16 = (unsigned short*)region; // E ushorts (dead after scount)
    uint2* h2 = (uint2*)region;                      // (N+1)*16 uint2

    size_t region_ints = (size_t)(n_nodes + 1) * 32;
    size_t arrS_ints = ((size_t)n_edges + 1) / 2;
    if (arrS_ints > region_ints) region_ints = arrS_ints;
    size_t need = ((size_t)n_nodes + 8 * (size_t)K + 8 * SBMAX + (K + 1) + K
                   + (SBMAX + 1) + SBMAX + (size_t)n_edges + region_ints) * sizeof(int);

    if (ws_size >= need && nb <= K && nb2 <= SBMAX) {
        zero_ints<<<32, block, 0, stream>>>(dbcnt8, 8 * K + 8 * SBMAX);
        bcnt_kernel<<<384, block, 0, stream>>>(src, dst, n_edges, dbcnt8, sbcnt8);
        scan2_kernel<<<2, K, 0, stream>>>(dbcnt8, sbcnt8, dbstart, gcursor,
                                          sbstart, scursor, n_edges);
        int pblocks = (n_edges + CHUNK - 1) / CHUNK;
        dualpart_kernel<<<pblocks, 256, 0, stream>>>(src, dst, n_edges, gcursor,
                                                     scursor, arrA, arrS16);
        scount_kernel<<<nb2, 256, 0, stream>>>(arrS16, sbstart, oscale, n_nodes);
        int n_total = (n_nodes + 1) * 16;
        h_prepass_kernel<<<2048, block, 0, stream>>>((const float4*)emb, oscale,
                                                     h2, n_total, n_nodes);
        sortagg_kernel<<<2 * nb, 256, 0, stream>>>(h2, arrA, dbstart, out, n_nodes);
    } else {
        int* foutdeg = (int*)d_ws;
        int* findeg = foutdeg + n_nodes;
        long long n_out = (long long)n_nodes * D_FEAT;
        fb_zero<<<2048, block, 0, stream>>>(out, n_out, foutdeg, 2 * n_nodes);
        fb_degree<<<2048, block, 0, stream>>>(src, dst, n_edges, foutdeg, findeg);
        fb_scatter<<<2048, block, 0, stream>>>(emb, src, dst, foutdeg, out, n_edges);
        fb_scale<<<2048, block, 0, stream>>>(out, findeg, n_out);
    }
}

// Round 12
// 121.511 us; speedup vs baseline: 1.0752x; 1.0752x over previous
//
#include <hip/hip_runtime.h>
#include <hip/hip_fp16.h>

#define D_FEAT 64
#define NPB 128            // nodes per bucket (node >> 7)
#define NBMAX 1024         // bucket count both sides (pow2)
#define CHUNK 4096         // edges per partition block (arrA run = 4 ints)
#define EPT 16             // CHUNK / 256
#define CAPB 2816          // full-bucket register staging capacity (mean 2046 + 17 sigma)
#define CAPB_H 1536        // half-bucket srcS capacity (mean 1023 + ~16 sigma)
#define RPT 6              // ceil(CAPB / 512)

// ---------------- zero ----------------
__global__ void zero_ints(int* __restrict__ p, int n) {
    int i = blockIdx.x * blockDim.x + threadIdx.x;
    int stride = gridDim.x * blockDim.x;
    for (int j = i; j < n; j += stride) p[j] = 0;
}

// ---------------- bucket counts for BOTH sides ----------------
__global__ __launch_bounds__(256) void bcnt_kernel(
        const int* __restrict__ src, const int* __restrict__ dst, int n_edges,
        int* __restrict__ dbcnt8, int* __restrict__ sbcnt8) {
    __shared__ int ld[NBMAX];
    __shared__ int ls[NBMAX];
    int t = threadIdx.x;
    for (int i = t; i < NBMAX; i += 256) { ld[i] = 0; ls[i] = 0; }
    __syncthreads();
    int i0 = blockIdx.x * blockDim.x + t;
    int stride = gridDim.x * blockDim.x;
    for (int e = i0; e < n_edges; e += stride) {
        atomicAdd(&ld[dst[e] >> 7], 1);
        atomicAdd(&ls[src[e] >> 7], 1);
    }
    __syncthreads();
    int* dmy = dbcnt8 + (blockIdx.x & 7) * NBMAX;
    int* smy = sbcnt8 + (blockIdx.x & 7) * NBMAX;
    for (int i = t; i < NBMAX; i += 256) {
        if (ld[i]) atomicAdd(&dmy[i], ld[i]);
        if (ls[i]) atomicAdd(&smy[i], ls[i]);
    }
}

// ---------------- dual exclusive scan: block 0 = dst side, block 1 = src side ----
__global__ void scan2_kernel(const int* __restrict__ dbcnt8, const int* __restrict__ sbcnt8,
                             int* __restrict__ dbstart, int* __restrict__ gcursor,
                             int* __restrict__ sbstart, int* __restrict__ scursor,
                             int n_edges) {
    __shared__ int wsum[16];
    int t = threadIdx.x, lane = t & 63, w = t >> 6;
    const int* c8 = (blockIdx.x == 0) ? dbcnt8 : sbcnt8;
    int* bs = (blockIdx.x == 0) ? dbstart : sbstart;
    int* cur = (blockIdx.x == 0) ? gcursor : scursor;
    int v = 0;
    #pragma unroll
    for (int c = 0; c < 8; ++c) v += c8[c * NBMAX + t];
    int inc = v;
    #pragma unroll
    for (int off = 1; off < 64; off <<= 1) {
        int y = __shfl_up(inc, off);
        if (lane >= off) inc += y;
    }
    if (lane == 63) wsum[w] = inc;
    __syncthreads();
    int add = 0;
    #pragma unroll
    for (int i = 0; i < 15; ++i) if (i < w) add += wsum[i];
    int ex = add + inc - v;
    bs[t] = ex;
    cur[t] = ex;
    if (t == NBMAX - 1) bs[NBMAX] = n_edges;
}

// ---------------- fused dual partition (round-7/9 proven version) ----------------
// Phase D: arrA[pk = (src<<7)|(dst&127)] bucketed by dst>>7
// Phase S: arrS[src&127 byte] bucketed by src>>7  (same LDS reused)
__global__ __launch_bounds__(256) void dualpart_kernel(
        const int* __restrict__ src, const int* __restrict__ dst, int n_edges,
        int* __restrict__ gcursor, int* __restrict__ scursor,
        int* __restrict__ arrA, unsigned char* __restrict__ arrS) {
    __shared__ int lhist[NBMAX];
    __shared__ int lstart[NBMAX];
    __shared__ int ldelta[NBMAX];
    __shared__ int lcur[NBMAX];
    __shared__ int part[256];
    __shared__ int pkLDS[CHUNK];
    __shared__ unsigned short bktLDS[CHUNK];

    int t = threadIdx.x;
    long long cbase = (long long)blockIdx.x * CHUNK;
    int cnt = (n_edges - cbase < CHUNK) ? (int)(n_edges - cbase) : CHUNK;

    for (int i = t; i < NBMAX; i += 256) lhist[i] = 0;
    __syncthreads();

    int ssrc[EPT], sdst[EPT];
    #pragma unroll
    for (int i = 0; i < EPT; ++i) {
        long long e = cbase + t + i * 256;
        if (e < n_edges) {
            ssrc[i] = src[e];
            sdst[i] = dst[e];
            atomicAdd(&lhist[sdst[i] >> 7], 1);
        } else {
            ssrc[i] = -1;
            sdst[i] = -1;
        }
    }
    __syncthreads();

    // ---- phase D scan ----
    int b0 = 4 * t;
    int h0 = lhist[b0], h1 = lhist[b0 + 1], h2v = lhist[b0 + 2], h3 = lhist[b0 + 3];
    int tot = h0 + h1 + h2v + h3;
    part[t] = tot;
    __syncthreads();
    for (int off = 1; off < 256; off <<= 1) {
        int x = (t >= off) ? part[t - off] : 0;
        __syncthreads();
        part[t] += x;
        __syncthreads();
    }
    int ex = part[t] - tot;
    lstart[b0] = ex;
    lstart[b0 + 1] = ex + h0;
    lstart[b0 + 2] = ex + h0 + h1;
    lstart[b0 + 3] = ex + h0 + h1 + h2v;
    __syncthreads();
    for (int b = t; b < NBMAX; b += 256) {
        lcur[b] = lstart[b];
        int c = lhist[b];
        if (c > 0) ldelta[b] = atomicAdd(&gcursor[b], c) - lstart[b];
    }
    __syncthreads();
    #pragma unroll
    for (int i = 0; i < EPT; ++i) {
        if (sdst[i] >= 0) {
            int b = sdst[i] >> 7;
            int slot = atomicAdd(&lcur[b], 1);
            pkLDS[slot] = (ssrc[i] << 7) | (sdst[i] & 127);
            bktLDS[slot] = (unsigned short)b;
        }
    }
    __syncthreads();
    for (int j = t; j < cnt; j += 256) {
        int b = bktLDS[j];
        arrA[j + ldelta[b]] = pkLDS[j];
    }
    __syncthreads();

    // ---- phase S (reuse all LDS) ----
    for (int i = t; i < NBMAX; i += 256) lhist[i] = 0;
    __syncthreads();
    #pragma unroll
    for (int i = 0; i < EPT; ++i) {
        if (ssrc[i] >= 0) atomicAdd(&lhist[ssrc[i] >> 7], 1);
    }
    __syncthreads();
    h0 = lhist[b0]; h1 = lhist[b0 + 1]; h2v = lhist[b0 + 2]; h3 = lhist[b0 + 3];
    tot = h0 + h1 + h2v + h3;
    part[t] = tot;
    __syncthreads();
    for (int off = 1; off < 256; off <<= 1) {
        int x = (t >= off) ? part[t - off] : 0;
        __syncthreads();
        part[t] += x;
        __syncthreads();
    }
    ex = part[t] - tot;
    lstart[b0] = ex;
    lstart[b0 + 1] = ex + h0;
    lstart[b0 + 2] = ex + h0 + h1;
    lstart[b0 + 3] = ex + h0 + h1 + h2v;
    __syncthreads();
    for (int b = t; b < NBMAX; b += 256) {
        lcur[b] = lstart[b];
        int c = lhist[b];
        if (c > 0) ldelta[b] = atomicAdd(&scursor[b], c) - lstart[b];
    }
    __syncthreads();
    unsigned char* stg = (unsigned char*)pkLDS;
    #pragma unroll
    for (int i = 0; i < EPT; ++i) {
        if (ssrc[i] >= 0) {
            int b = ssrc[i] >> 7;
            int slot = atomicAdd(&lcur[b], 1);
            stg[slot] = (unsigned char)(ssrc[i] & 127);
            bktLDS[slot] = (unsigned short)b;
        }
    }
    __syncthreads();
    for (int j = t; j < cnt; j += 256) {
        int b = bktLDS[j];
        arrS[j + ldelta[b]] = stg[j];
    }
}

// ---------------- fused out-degree + h prepass: one block per src bucket ----------
__global__ __launch_bounds__(256) void prep_kernel(
        const float4* __restrict__ emb4, const unsigned char* __restrict__ arrS,
        const int* __restrict__ sbstart, uint2* __restrict__ h2, int n_nodes) {
    __shared__ int lh[NPB];
    __shared__ float lsc[NPB];
    int b = blockIdx.x, t = threadIdx.x;
    int s = sbstart[b], e = sbstart[b + 1];
    if (t < NPB) lh[t] = 0;
    __syncthreads();
    for (int i = s + t; i < e; i += 256) atomicAdd(&lh[arrS[i]], 1);
    __syncthreads();
    if (t < NPB) {
        int od = lh[t];
        lsc[t] = rsqrtf((float)(od > 1 ? od : 1));
    }
    __syncthreads();
    int nbase = b * NPB;
    int r = t >> 4, c = t & 15;
    for (int r0 = 0; r0 < NPB; r0 += 16) {
        int row = r0 + r;
        int node = nbase + row;
        if (node < n_nodes) {
            float sc = lsc[row];
            float4 v = emb4[(size_t)node * 16 + c];
            __half2 a = __floats2half2_rn(v.x * sc, v.y * sc);
            __half2 bb = __floats2half2_rn(v.z * sc, v.w * sc);
            union { __half2 h; unsigned int u; } ua, ub;
            ua.h = a; ub.h = bb;
            uint2 rr; rr.x = ua.u; rr.y = ub.u;
            h2[(size_t)node * 16 + c] = rr;
        }
    }
    if (b == 0 && t < 16) {
        uint2 z; z.x = 0; z.y = 0;
        h2[(size_t)n_nodes * 16 + t] = z;
    }
}

// ---------------- fused sort + aggregate: 2 blocks/bucket, 512 thr, reg staging ---
__global__ __launch_bounds__(512) void sortagg_kernel(
        const uint2* __restrict__ h2, const int* __restrict__ arrA,
        const int* __restrict__ dbstart, float* __restrict__ out, int n_nodes) {
    __shared__ int lh[64];
    __shared__ int lst[64];
    __shared__ int lcur[64];
    __shared__ int srcS[CAPB_H];
    int b = blockIdx.x >> 1, half = blockIdx.x & 1;
    int t = threadIdx.x;
    int s = dbstart[b], e = dbstart[b + 1];
    int cnt = e - s;
    bool fit = (cnt <= CAPB);

    if (t < 64) lh[t] = 0;
    __syncthreads();
    int pkreg[RPT];
    if (fit) {
        #pragma unroll
        for (int i = 0; i < RPT; ++i) {
            int idx = t + i * 512;
            int pk = (idx < cnt) ? arrA[s + idx] : -1;
            pkreg[i] = pk;
            if (pk >= 0 && (((pk >> 6) & 1) == half)) atomicAdd(&lh[pk & 63], 1);
        }
    } else {
        for (int i = t; i < cnt; i += 512) {
            int v = arrA[s + i];
            if (((v >> 6) & 1) == half) atomicAdd(&lh[v & 63], 1);
        }
    }
    __syncthreads();
    if (t < 64) {
        int l0 = lh[t];
        int a = l0;
        #pragma unroll
        for (int off = 1; off < 64; off <<= 1) {
            int y = __shfl_up(a, off);
            if (t >= off) a += y;
        }
        lst[t] = a - l0;
        lcur[t] = a - l0;
    }
    __syncthreads();
    int halfcnt = lst[63] + lh[63];
    bool useS = fit && (halfcnt <= CAPB_H);
    if (useS) {
        #pragma unroll
        for (int i = 0; i < RPT; ++i) {
            int pk = pkreg[i];
            if (pk >= 0 && (((pk >> 6) & 1) == half)) {
                int slot = atomicAdd(&lcur[pk & 63], 1);
                srcS[slot] = pk >> 7;
            }
        }
    }
    __syncthreads();

    int w = t >> 6, L = t & 63, g = L >> 4, c = L & 15;
    int nbase = b * NPB + half * 64;
    union { unsigned int u; __half2 h; } uc;
    for (int nl = w * 8; nl < w * 8 + 8; ++nl) {
        int node = nbase + nl;
        if (node >= n_nodes) break;
        int st = lst[nl];
        int deg = lh[nl];
        int en = st + deg;
        float ax = 0.f, ay = 0.f, az = 0.f, aw = 0.f;
        if (useS) {
            for (int eidx = st; eidx < en; eidx += 16) {
                int ea = eidx + g, eb = ea + 4, ec = ea + 8, ed = ea + 12;
                int sa = (ea < en) ? srcS[ea] : n_nodes;
                int sb = (eb < en) ? srcS[eb] : n_nodes;
                int sc = (ec < en) ? srcS[ec] : n_nodes;
                int sd = (ed < en) ? srcS[ed] : n_nodes;
                uint2 va = h2[(size_t)sa * 16 + c];
                uint2 vb = h2[(size_t)sb * 16 + c];
                uint2 vc = h2[(size_t)sc * 16 + c];
                uint2 vd = h2[(size_t)sd * 16 + c];
                float2 f;
                uc.u = va.x; f = __half22float2(uc.h); ax += f.x; ay += f.y;
                uc.u = va.y; f = __half22float2(uc.h); az += f.x; aw += f.y;
                uc.u = vb.x; f = __half22float2(uc.h); ax += f.x; ay += f.y;
                uc.u = vb.y; f = __half22float2(uc.h); az += f.x; aw += f.y;
                uc.u = vc.x; f = __half22float2(uc.h); ax += f.x; ay += f.y;
                uc.u = vc.y; f = __half22float2(uc.h); az += f.x; aw += f.y;
                uc.u = vd.x; f = __half22float2(uc.h); ax += f.x; ay += f.y;
                uc.u = vd.y; f = __half22float2(uc.h); az += f.x; aw += f.y;
            }
        } else {
            int hv = (half << 6) | nl;
            for (int i2 = g; i2 < cnt; i2 += 4) {
                int v = arrA[s + i2];
                if ((v & 127) == hv) {
                    int sa = v >> 7;
                    uint2 va = h2[(size_t)sa * 16 + c];
                    float2 f;
                    uc.u = va.x; f = __half22float2(uc.h); ax += f.x; ay += f.y;
                    uc.u = va.y; f = __half22float2(uc.h); az += f.x; aw += f.y;
                }
            }
        }
        ax += __shfl_xor(ax, 16); ay += __shfl_xor(ay, 16);
        az += __shfl_xor(az, 16); aw += __shfl_xor(aw, 16);
        ax += __shfl_xor(ax, 32); ay += __shfl_xor(ay, 32);
        az += __shfl_xor(az, 32); aw += __shfl_xor(aw, 32);
        if (g == 0) {
            float is = rsqrtf((float)(deg > 1 ? deg : 1));
            float4 r;
            r.x = ax * is; r.y = ay * is; r.z = az * is; r.w = aw * is;
            ((float4*)out)[(size_t)node * 16 + c] = r;
        }
    }
}

// ---------------- fallback: atomic scatter path (tiny ws) ----------------
__global__ void fb_zero(float* __restrict__ out, long long n_out,
                        int* __restrict__ deg, int n_deg) {
    long long i = (long long)blockIdx.x * blockDim.x + threadIdx.x;
    long long stride = (long long)gridDim.x * blockDim.x;
    for (long long j = i; j < n_out; j += stride) out[j] = 0.0f;
    for (long long j = i; j < n_deg; j += stride) deg[j] = 0;
}

__global__ void fb_degree(const int* __restrict__ src, const int* __restrict__ dst,
                          int n_edges, int* __restrict__ outdeg, int* __restrict__ indeg) {
    int i = blockIdx.x * blockDim.x + threadIdx.x;
    int stride = gridDim.x * blockDim.x;
    for (int e = i; e < n_edges; e += stride) {
        atomicAdd(&outdeg[src[e]], 1);
        atomicAdd(&indeg[dst[e]], 1);
    }
}

__global__ void fb_scatter(const float* __restrict__ emb,
                           const int* __restrict__ src, const int* __restrict__ dst,
                           const int* __restrict__ outdeg,
                           float* __restrict__ out, int n_edges) {
    const int epb = blockDim.x >> 6;
    const int d = threadIdx.x & 63;
    long long e0 = (long long)blockIdx.x * epb + (threadIdx.x >> 6);
    long long estride = (long long)gridDim.x * epb;
    for (long long e = e0; e < n_edges; e += estride) {
        int s = src[e];
        int tt = dst[e];
        int od = outdeg[s];
        float v = emb[(long long)s * D_FEAT + d] * rsqrtf((float)(od > 1 ? od : 1));
        atomicAdd(&out[(long long)tt * D_FEAT + d], v);
    }
}

__global__ void fb_scale(float* __restrict__ out, const int* __restrict__ indeg,
                         long long n_elems) {
    long long i = (long long)blockIdx.x * blockDim.x + threadIdx.x;
    long long stride = (long long)gridDim.x * blockDim.x;
    for (long long j = i; j < n_elems; j += stride) {
        int id = indeg[(int)(j >> 6)];
        out[j] *= rsqrtf((float)(id > 1 ? id : 1));
    }
}

extern "C" void kernel_launch(void* const* d_in, const int* in_sizes, int n_in,
                              void* d_out, int out_size, void* d_ws, size_t ws_size,
                              hipStream_t stream) {
    const float* emb = (const float*)d_in[0];
    const int* src = (const int*)d_in[1];
    const int* dst = (const int*)d_in[2];
    const int n_nodes = in_sizes[0] / D_FEAT;
    const int n_edges = in_sizes[1];
    float* out = (float*)d_out;
    const int block = 256;
    const int nb = (n_nodes + NPB - 1) / NPB;
    const int K = NBMAX;

    // layout (ints): dbcnt8 | sbcnt8 | dbstart | gcursor | sbstart | scursor |
    //                arrA | region{arrS bytes -> h2}
    int* dbcnt8 = (int*)d_ws;                        // 8K
    int* sbcnt8 = dbcnt8 + 8 * K;                    // 8K
    int* dbstart = sbcnt8 + 8 * K;                   // K+1
    int* gcursor = dbstart + K + 1;                  // K
    int* sbstart = gcursor + K;                      // K+1
    int* scursor = sbstart + K + 1;                  // K
    int* arrA = scursor + K;                         // E
    int* region = arrA + n_edges;                    // max(E/4, (N+1)*32) ints
    unsigned char* arrS = (unsigned char*)region;    // E bytes (dead after prep)
    uint2* h2 = (uint2*)region;                      // (N+1)*16 uint2

    size_t region_ints = (size_t)(n_nodes + 1) * 32;
    size_t arrS_ints = ((size_t)n_edges + 3) / 4;
    if (arrS_ints > region_ints) region_ints = arrS_ints;
    size_t need = (16 * (size_t)K + 2 * (size_t)(K + 1) + 2 * (size_t)K
                   + (size_t)n_edges + region_ints) * sizeof(int);

    if (ws_size >= need && nb <= K) {
        zero_ints<<<32, block, 0, stream>>>(dbcnt8, 16 * K);
        bcnt_kernel<<<384, block, 0, stream>>>(src, dst, n_edges, dbcnt8, sbcnt8);
        scan2_kernel<<<2, K, 0, stream>>>(dbcnt8, sbcnt8, dbstart, gcursor,
                                          sbstart, scursor, n_edges);
        int pblocks = (n_edges + CHUNK - 1) / CHUNK;
        dualpart_kernel<<<pblocks, 256, 0, stream>>>(src, dst, n_edges, gcursor,
                                                     scursor, arrA, arrS);
        prep_kernel<<<nb, 256, 0, stream>>>((const float4*)emb, arrS, sbstart,
                                            h2, n_nodes);
        sortagg_kernel<<<2 * nb, 512, 0, stream>>>(h2, arrA, dbstart, out, n_nodes);
    } else {
        int* foutdeg = (int*)d_ws;
        int* findeg = foutdeg + n_nodes;
        long long n_out = (long long)n_nodes * D_FEAT;
        fb_zero<<<2048, block, 0, stream>>>(out, n_out, foutdeg, 2 * n_nodes);
        fb_degree<<<2048, block, 0, stream>>>(src, dst, n_edges, foutdeg, findeg);
        fb_scatter<<<2048, block, 0, stream>>>(emb, src, dst, foutdeg, out, n_edges);
        fb_scale<<<2048, block, 0, stream>>>(out, findeg, n_out);
    }
}

// Round 13
// 116.650 us; speedup vs baseline: 1.1200x; 1.0417x over previous
//
#include <hip/hip_runtime.h>
#include <hip/hip_fp16.h>

#define D_FEAT 64
#define NPB 128            // nodes per bucket (node >> 7)
#define NBMAX 1024         // bucket count both sides (pow2)
#define CHUNK 8192         // edges per partition block (arrA run = 8 ints = 32B)
#define EPT 32             // CHUNK / 256
#define CAPB 2816          // full-bucket register staging capacity
#define CAPB_H 1536        // half-bucket srcS capacity (mean 1023 + ~16 sigma)
#define RPT 6              // ceil(CAPB / 512)

// ---------------- zero ----------------
__global__ void zero_ints(int* __restrict__ p, int n) {
    int i = blockIdx.x * blockDim.x + threadIdx.x;
    int stride = gridDim.x * blockDim.x;
    for (int j = i; j < n; j += stride) p[j] = 0;
}

// ---------------- bucket counts for BOTH sides ----------------
__global__ __launch_bounds__(256) void bcnt_kernel(
        const int* __restrict__ src, const int* __restrict__ dst, int n_edges,
        int* __restrict__ dbcnt8, int* __restrict__ sbcnt8) {
    __shared__ int ld[NBMAX];
    __shared__ int ls[NBMAX];
    int t = threadIdx.x;
    for (int i = t; i < NBMAX; i += 256) { ld[i] = 0; ls[i] = 0; }
    __syncthreads();
    int i0 = blockIdx.x * blockDim.x + t;
    int stride = gridDim.x * blockDim.x;
    for (int e = i0; e < n_edges; e += stride) {
        atomicAdd(&ld[dst[e] >> 7], 1);
        atomicAdd(&ls[src[e] >> 7], 1);
    }
    __syncthreads();
    int* dmy = dbcnt8 + (blockIdx.x & 7) * NBMAX;
    int* smy = sbcnt8 + (blockIdx.x & 7) * NBMAX;
    for (int i = t; i < NBMAX; i += 256) {
        if (ld[i]) atomicAdd(&dmy[i], ld[i]);
        if (ls[i]) atomicAdd(&smy[i], ls[i]);
    }
}

// ---------------- dual exclusive scan: block 0 = dst side, block 1 = src side ----
__global__ void scan2_kernel(const int* __restrict__ dbcnt8, const int* __restrict__ sbcnt8,
                             int* __restrict__ dbstart, int* __restrict__ gcursor,
                             int* __restrict__ sbstart, int* __restrict__ scursor,
                             int n_edges) {
    __shared__ int wsum[16];
    int t = threadIdx.x, lane = t & 63, w = t >> 6;
    const int* c8 = (blockIdx.x == 0) ? dbcnt8 : sbcnt8;
    int* bs = (blockIdx.x == 0) ? dbstart : sbstart;
    int* cur = (blockIdx.x == 0) ? gcursor : scursor;
    int v = 0;
    #pragma unroll
    for (int c = 0; c < 8; ++c) v += c8[c * NBMAX + t];
    int inc = v;
    #pragma unroll
    for (int off = 1; off < 64; off <<= 1) {
        int y = __shfl_up(inc, off);
        if (lane >= off) inc += y;
    }
    if (lane == 63) wsum[w] = inc;
    __syncthreads();
    int add = 0;
    #pragma unroll
    for (int i = 0; i < 15; ++i) if (i < w) add += wsum[i];
    int ex = add + inc - v;
    bs[t] = ex;
    cur[t] = ex;
    if (t == NBMAX - 1) bs[NBMAX] = n_edges;
}

// ---------------- fused dual partition (CHUNK=8192 for 2x write-run length) ------
// Phase D: arrA[pk = (src<<7)|(dst&127)] bucketed by dst>>7
// Phase S: arrS[src&127 byte] bucketed by src>>7  (same LDS reused)
__global__ __launch_bounds__(256) void dualpart_kernel(
        const int* __restrict__ src, const int* __restrict__ dst, int n_edges,
        int* __restrict__ gcursor, int* __restrict__ scursor,
        int* __restrict__ arrA, unsigned char* __restrict__ arrS) {
    __shared__ int lhist[NBMAX];
    __shared__ int lstart[NBMAX];
    __shared__ int ldelta[NBMAX];
    __shared__ int lcur[NBMAX];
    __shared__ int part[256];
    __shared__ int pkLDS[CHUNK];
    __shared__ unsigned short bktLDS[CHUNK];

    int t = threadIdx.x;
    long long cbase = (long long)blockIdx.x * CHUNK;
    int cnt = (n_edges - cbase < CHUNK) ? (int)(n_edges - cbase) : CHUNK;

    for (int i = t; i < NBMAX; i += 256) lhist[i] = 0;
    __syncthreads();

    int ssrc[EPT], sdst[EPT];
    #pragma unroll
    for (int i = 0; i < EPT; ++i) {
        long long e = cbase + t + i * 256;
        if (e < n_edges) {
            ssrc[i] = src[e];
            sdst[i] = dst[e];
            atomicAdd(&lhist[sdst[i] >> 7], 1);
        } else {
            ssrc[i] = -1;
            sdst[i] = -1;
        }
    }
    __syncthreads();

    // ---- phase D scan ----
    int b0 = 4 * t;
    int h0 = lhist[b0], h1 = lhist[b0 + 1], h2v = lhist[b0 + 2], h3 = lhist[b0 + 3];
    int tot = h0 + h1 + h2v + h3;
    part[t] = tot;
    __syncthreads();
    for (int off = 1; off < 256; off <<= 1) {
        int x = (t >= off) ? part[t - off] : 0;
        __syncthreads();
        part[t] += x;
        __syncthreads();
    }
    int ex = part[t] - tot;
    lstart[b0] = ex;
    lstart[b0 + 1] = ex + h0;
    lstart[b0 + 2] = ex + h0 + h1;
    lstart[b0 + 3] = ex + h0 + h1 + h2v;
    __syncthreads();
    for (int b = t; b < NBMAX; b += 256) {
        lcur[b] = lstart[b];
        int c = lhist[b];
        if (c > 0) ldelta[b] = atomicAdd(&gcursor[b], c) - lstart[b];
    }
    __syncthreads();
    #pragma unroll
    for (int i = 0; i < EPT; ++i) {
        if (sdst[i] >= 0) {
            int b = sdst[i] >> 7;
            int slot = atomicAdd(&lcur[b], 1);
            pkLDS[slot] = (ssrc[i] << 7) | (sdst[i] & 127);
            bktLDS[slot] = (unsigned short)b;
        }
    }
    __syncthreads();
    for (int j = t; j < cnt; j += 256) {
        int b = bktLDS[j];
        arrA[j + ldelta[b]] = pkLDS[j];
    }
    __syncthreads();

    // ---- phase S (reuse all LDS) ----
    for (int i = t; i < NBMAX; i += 256) lhist[i] = 0;
    __syncthreads();
    #pragma unroll
    for (int i = 0; i < EPT; ++i) {
        if (ssrc[i] >= 0) atomicAdd(&lhist[ssrc[i] >> 7], 1);
    }
    __syncthreads();
    h0 = lhist[b0]; h1 = lhist[b0 + 1]; h2v = lhist[b0 + 2]; h3 = lhist[b0 + 3];
    tot = h0 + h1 + h2v + h3;
    part[t] = tot;
    __syncthreads();
    for (int off = 1; off < 256; off <<= 1) {
        int x = (t >= off) ? part[t - off] : 0;
        __syncthreads();
        part[t] += x;
        __syncthreads();
    }
    ex = part[t] - tot;
    lstart[b0] = ex;
    lstart[b0 + 1] = ex + h0;
    lstart[b0 + 2] = ex + h0 + h1;
    lstart[b0 + 3] = ex + h0 + h1 + h2v;
    __syncthreads();
    for (int b = t; b < NBMAX; b += 256) {
        lcur[b] = lstart[b];
        int c = lhist[b];
        if (c > 0) ldelta[b] = atomicAdd(&scursor[b], c) - lstart[b];
    }
    __syncthreads();
    unsigned char* stg = (unsigned char*)pkLDS;
    #pragma unroll
    for (int i = 0; i < EPT; ++i) {
        if (ssrc[i] >= 0) {
            int b = ssrc[i] >> 7;
            int slot = atomicAdd(&lcur[b], 1);
            stg[slot] = (unsigned char)(ssrc[i] & 127);
            bktLDS[slot] = (unsigned short)b;
        }
    }
    __syncthreads();
    for (int j = t; j < cnt; j += 256) {
        int b = bktLDS[j];
        arrS[j + ldelta[b]] = stg[j];
    }
}

// ---------------- out-degree -> oscale (one block per src bucket, race-free) ------
__global__ __launch_bounds__(256) void scount_kernel(
        const unsigned char* __restrict__ arrS, const int* __restrict__ sbstart,
        float* __restrict__ oscale, int n_nodes) {
    __shared__ int lh[NPB];
    int b = blockIdx.x, t = threadIdx.x;
    int s = sbstart[b], e = sbstart[b + 1];
    if (t < NPB) lh[t] = 0;
    __syncthreads();
    for (int i = s + t; i < e; i += 256) atomicAdd(&lh[arrS[i]], 1);
    __syncthreads();
    if (t < NPB) {
        int node = b * NPB + t;
        if (node < n_nodes) {
            int od = lh[t];
            oscale[node] = rsqrtf((float)(od > 1 ? od : 1));
        }
    }
}

// ---------------- h prepass (grid-stride; h2 overwrites arrS only after scount) ---
__global__ void h_prepass_kernel(const float4* __restrict__ emb4,
                                 const float* __restrict__ oscale,
                                 uint2* __restrict__ h2, int n_total, int n_nodes) {
    int i = blockIdx.x * blockDim.x + threadIdx.x;
    int stride = gridDim.x * blockDim.x;
    for (int j = i; j < n_total; j += stride) {
        int node = j >> 4;
        uint2 r;
        if (node < n_nodes) {
            float s = oscale[node];
            float4 v = emb4[j];
            __half2 a = __floats2half2_rn(v.x * s, v.y * s);
            __half2 b = __floats2half2_rn(v.z * s, v.w * s);
            union { __half2 h; unsigned int u; } ua, ub;
            ua.h = a; ub.h = b;
            r.x = ua.u; r.y = ub.u;
        } else {
            r.x = 0; r.y = 0;
        }
        h2[j] = r;
    }
}

// ---------------- fused sort + aggregate: 2 blocks/bucket, 512 thr, reg staging ---
__global__ __launch_bounds__(512) void sortagg_kernel(
        const uint2* __restrict__ h2, const int* __restrict__ arrA,
        const int* __restrict__ dbstart, float* __restrict__ out, int n_nodes) {
    __shared__ int lh[64];
    __shared__ int lst[64];
    __shared__ int lcur[64];
    __shared__ int srcS[CAPB_H];
    int b = blockIdx.x >> 1, half = blockIdx.x & 1;
    int t = threadIdx.x;
    int s = dbstart[b], e = dbstart[b + 1];
    int cnt = e - s;
    bool fit = (cnt <= CAPB);

    if (t < 64) lh[t] = 0;
    __syncthreads();
    int pkreg[RPT];
    if (fit) {
        #pragma unroll
        for (int i = 0; i < RPT; ++i) {
            int idx = t + i * 512;
            int pk = (idx < cnt) ? arrA[s + idx] : -1;
            pkreg[i] = pk;
            if (pk >= 0 && (((pk >> 6) & 1) == half)) atomicAdd(&lh[pk & 63], 1);
        }
    } else {
        for (int i = t; i < cnt; i += 512) {
            int v = arrA[s + i];
            if (((v >> 6) & 1) == half) atomicAdd(&lh[v & 63], 1);
        }
    }
    __syncthreads();
    if (t < 64) {
        int l0 = lh[t];
        int a = l0;
        #pragma unroll
        for (int off = 1; off < 64; off <<= 1) {
            int y = __shfl_up(a, off);
            if (t >= off) a += y;
        }
        lst[t] = a - l0;
        lcur[t] = a - l0;
    }
    __syncthreads();
    int halfcnt = lst[63] + lh[63];
    bool useS = fit && (halfcnt <= CAPB_H);
    if (useS) {
        #pragma unroll
        for (int i = 0; i < RPT; ++i) {
            int pk = pkreg[i];
            if (pk >= 0 && (((pk >> 6) & 1) == half)) {
                int slot = atomicAdd(&lcur[pk & 63], 1);
                srcS[slot] = pk >> 7;
            }
        }
    }
    __syncthreads();

    int w = t >> 6, L = t & 63, g = L >> 4, c = L & 15;
    int nbase = b * NPB + half * 64;
    union { unsigned int u; __half2 h; } uc;
    for (int nl = w * 8; nl < w * 8 + 8; ++nl) {
        int node = nbase + nl;
        if (node >= n_nodes) break;
        int st = lst[nl];
        int deg = lh[nl];
        int en = st + deg;
        float ax = 0.f, ay = 0.f, az = 0.f, aw = 0.f;
        if (useS) {
            for (int eidx = st; eidx < en; eidx += 16) {
                int ea = eidx + g, eb = ea + 4, ec = ea + 8, ed = ea + 12;
                int sa = (ea < en) ? srcS[ea] : n_nodes;
                int sb = (eb < en) ? srcS[eb] : n_nodes;
                int sc = (ec < en) ? srcS[ec] : n_nodes;
                int sd = (ed < en) ? srcS[ed] : n_nodes;
                uint2 va = h2[(size_t)sa * 16 + c];
                uint2 vb = h2[(size_t)sb * 16 + c];
                uint2 vc = h2[(size_t)sc * 16 + c];
                uint2 vd = h2[(size_t)sd * 16 + c];
                float2 f;
                uc.u = va.x; f = __half22float2(uc.h); ax += f.x; ay += f.y;
                uc.u = va.y; f = __half22float2(uc.h); az += f.x; aw += f.y;
                uc.u = vb.x; f = __half22float2(uc.h); ax += f.x; ay += f.y;
                uc.u = vb.y; f = __half22float2(uc.h); az += f.x; aw += f.y;
                uc.u = vc.x; f = __half22float2(uc.h); ax += f.x; ay += f.y;
                uc.u = vc.y; f = __half22float2(uc.h); az += f.x; aw += f.y;
                uc.u = vd.x; f = __half22float2(uc.h); ax += f.x; ay += f.y;
                uc.u = vd.y; f = __half22float2(uc.h); az += f.x; aw += f.y;
            }
        } else {
            int hv = (half << 6) | nl;
            for (int i2 = g; i2 < cnt; i2 += 4) {
                int v = arrA[s + i2];
                if ((v & 127) == hv) {
                    int sa = v >> 7;
                    uint2 va = h2[(size_t)sa * 16 + c];
                    float2 f;
                    uc.u = va.x; f = __half22float2(uc.h); ax += f.x; ay += f.y;
                    uc.u = va.y; f = __half22float2(uc.h); az += f.x; aw += f.y;
                }
            }
        }
        ax += __shfl_xor(ax, 16); ay += __shfl_xor(ay, 16);
        az += __shfl_xor(az, 16); aw += __shfl_xor(aw, 16);
        ax += __shfl_xor(ax, 32); ay += __shfl_xor(ay, 32);
        az += __shfl_xor(az, 32); aw += __shfl_xor(aw, 32);
        if (g == 0) {
            float is = rsqrtf((float)(deg > 1 ? deg : 1));
            float4 r;
            r.x = ax * is; r.y = ay * is; r.z = az * is; r.w = aw * is;
            ((float4*)out)[(size_t)node * 16 + c] = r;
        }
    }
}

// ---------------- fallback: atomic scatter path (tiny ws) ----------------
__global__ void fb_zero(float* __restrict__ out, long long n_out,
                        int* __restrict__ deg, int n_deg) {
    long long i = (long long)blockIdx.x * blockDim.x + threadIdx.x;
    long long stride = (long long)gridDim.x * blockDim.x;
    for (long long j = i; j < n_out; j += stride) out[j] = 0.0f;
    for (long long j = i; j < n_deg; j += stride) deg[j] = 0;
}

__global__ void fb_degree(const int* __restrict__ src, const int* __restrict__ dst,
                          int n_edges, int* __restrict__ outdeg, int* __restrict__ indeg) {
    int i = blockIdx.x * blockDim.x + threadIdx.x;
    int stride = gridDim.x * blockDim.x;
    for (int e = i; e < n_edges; e += stride) {
        atomicAdd(&outdeg[src[e]], 1);
        atomicAdd(&indeg[dst[e]], 1);
    }
}

__global__ void fb_scatter(const float* __restrict__ emb,
                           const int* __restrict__ src, const int* __restrict__ dst,
                           const int* __restrict__ outdeg,
                           float* __restrict__ out, int n_edges) {
    const int epb = blockDim.x >> 6;
    const int d = threadIdx.x & 63;
    long long e0 = (long long)blockIdx.x * epb + (threadIdx.x >> 6);
    long long estride = (long long)gridDim.x * epb;
    for (long long e = e0; e < n_edges; e += estride) {
        int s = src[e];
        int tt = dst[e];
        int od = outdeg[s];
        float v = emb[(long long)s * D_FEAT + d] * rsqrtf((float)(od > 1 ? od : 1));
        atomicAdd(&out[(long long)tt * D_FEAT + d], v);
    }
}

__global__ void fb_scale(float* __restrict__ out, const int* __restrict__ indeg,
                         long long n_elems) {
    long long i = (long long)blockIdx.x * blockDim.x + threadIdx.x;
    long long stride = (long long)gridDim.x * blockDim.x;
    for (long long j = i; j < n_elems; j += stride) {
        int id = indeg[(int)(j >> 6)];
        out[j] *= rsqrtf((float)(id > 1 ? id : 1));
    }
}

extern "C" void kernel_launch(void* const* d_in, const int* in_sizes, int n_in,
                              void* d_out, int out_size, void* d_ws, size_t ws_size,
                              hipStream_t stream) {
    const float* emb = (const float*)d_in[0];
    const int* src = (const int*)d_in[1];
    const int* dst = (const int*)d_in[2];
    const int n_nodes = in_sizes[0] / D_FEAT;
    const int n_edges = in_sizes[1];
    float* out = (float*)d_out;
    const int block = 256;
    const int nb = (n_nodes + NPB - 1) / NPB;
    const int K = NBMAX;

    // layout (ints): oscale | dbcnt8 | sbcnt8 | dbstart | gcursor | sbstart |
    //                scursor | arrA | region{arrS bytes -> h2}
    float* oscale = (float*)d_ws;                    // N
    int* dbcnt8 = (int*)(oscale + n_nodes);          // 8K
    int* sbcnt8 = dbcnt8 + 8 * K;                    // 8K
    int* dbstart = sbcnt8 + 8 * K;                   // K+1
    int* gcursor = dbstart + K + 1;                  // K
    int* sbstart = gcursor + K;                      // K+1
    int* scursor = sbstart + K + 1;                  // K
    int* arrA = scursor + K;                         // E
    int* region = arrA + n_edges;                    // max(E/4, (N+1)*32) ints
    unsigned char* arrS = (unsigned char*)region;    // E bytes (consumed by scount)
    uint2* h2 = (uint2*)region;                      // (N+1)*16 uint2 (after scount)

    size_t region_ints = (size_t)(n_nodes + 1) * 32;
    size_t arrS_ints = ((size_t)n_edges + 3) / 4;
    if (arrS_ints > region_ints) region_ints = arrS_ints;
    size_t need = ((size_t)n_nodes + 16 * (size_t)K + 2 * (size_t)(K + 1) + 2 * (size_t)K
                   + (size_t)n_edges + region_ints) * sizeof(int);

    if (ws_size >= need && nb <= K) {
        zero_ints<<<32, block, 0, stream>>>(dbcnt8, 16 * K);
        bcnt_kernel<<<384, block, 0, stream>>>(src, dst, n_edges, dbcnt8, sbcnt8);
        scan2_kernel<<<2, K, 0, stream>>>(dbcnt8, sbcnt8, dbstart, gcursor,
                                          sbstart, scursor, n_edges);
        int pblocks = (n_edges + CHUNK - 1) / CHUNK;
        dualpart_kernel<<<pblocks, 256, 0, stream>>>(src, dst, n_edges, gcursor,
                                                     scursor, arrA, arrS);
        scount_kernel<<<nb, 256, 0, stream>>>(arrS, sbstart, oscale, n_nodes);
        int n_total = (n_nodes + 1) * 16;
        h_prepass_kernel<<<2048, block, 0, stream>>>((const float4*)emb, oscale,
                                                     h2, n_total, n_nodes);
        sortagg_kernel<<<2 * nb, 512, 0, stream>>>(h2, arrA, dbstart, out, n_nodes);
    } else {
        int* foutdeg = (int*)d_ws;
        int* findeg = foutdeg + n_nodes;
        long long n_out = (long long)n_nodes * D_FEAT;
        fb_zero<<<2048, block, 0, stream>>>(out, n_out, foutdeg, 2 * n_nodes);
        fb_degree<<<2048, block, 0, stream>>>(src, dst, n_edges, foutdeg, findeg);
        fb_scatter<<<2048, block, 0, stream>>>(emb, src, dst, foutdeg, out, n_edges);
        fb_scale<<<2048, block, 0, stream>>>(out, findeg, n_out);
    }
}